// Round 4
// baseline (2427.350 us; speedup 1.0000x reference)
//
#include <hip/hip_runtime.h>
#include <math.h>

#define BN 32768
#define DN 256
#define KN 8192
#define CAP 2000000u

// Output layout (floats, concatenated in reference return order)
#define O_LOSS 8388608       // BN*DN
#define O_IDX  8388609
#define O_PERP 8421377       // O_IDX + BN
#define O_EMB  8421378
#define O_CS   10518530      // O_EMB + KN*DN
#define O_ES   10526722      // O_CS + KN

typedef _Float16 half_t;
typedef __attribute__((ext_vector_type(4))) _Float16 half4v;
typedef __attribute__((ext_vector_type(8))) _Float16 half8;
typedef __attribute__((ext_vector_type(16))) float float16v;
typedef unsigned long long u64;
typedef unsigned int u32;

__device__ __forceinline__ float wave_reduce_add(float v) {
#pragma unroll
  for (int off = 32; off > 0; off >>= 1) v += __shfl_down(v, off);
  return v;
}

// total-order transforms: enc monotone float->u32, dec its inverse
__device__ __forceinline__ u32 enc_f(float d) {
  u32 fb = __float_as_uint(d);
  return fb ^ ((fb >> 31) ? 0xFFFFFFFFu : 0x80000000u);
}
__device__ __forceinline__ float dec_key(u32 u) {
  return __uint_as_float((u & 0x80000000u) ? (u ^ 0x80000000u) : ~u);
}

// pack z hi-half into tile-major layout [tile128][kg32][row128][8] + row norms
__global__ __launch_bounds__(256) void k_prep_z(const float* __restrict__ z,
                                                half_t* __restrict__ zh,
                                                float* __restrict__ znh,
                                                float* __restrict__ znl) {
  const int wid = threadIdx.x >> 6, lane = threadIdx.x & 63;
  const int row = blockIdx.x * 4 + wid;
  float4 v = *(const float4*)(z + (size_t)row * DN + lane * 4);
  float xs[4] = {v.x, v.y, v.z, v.w};
  half4v hv;
  float h2 = 0.f, l2 = 0.f;
#pragma unroll
  for (int j = 0; j < 4; ++j) {
    half_t hh = (half_t)xs[j];
    float lf = xs[j] - (float)hh;
    hv[j] = hh;
    h2 += (float)hh * (float)hh;
    l2 += lf * lf;
  }
  const int tile = row >> 7, r = row & 127, kg = lane >> 1, off = (lane & 1) * 4;
  *(half4v*)(zh + (size_t)tile * 32768 + kg * 1024 + r * 8 + off) = hv;
#pragma unroll
  for (int o = 32; o > 0; o >>= 1) {
    h2 += __shfl_down(h2, o);
    l2 += __shfl_down(l2, o);
  }
  if (lane == 0) {
    znh[row] = sqrtf(h2);
    znl[row] = sqrtf(l2);
  }
}

// pack e hi-half + fp32 ||e||^2 + global max hi/lo norms (as float bits)
__global__ __launch_bounds__(256) void k_prep_e(const float* __restrict__ e,
                                                half_t* __restrict__ eh,
                                                float* __restrict__ enorm,
                                                u32* __restrict__ Wb) {
  const int wid = threadIdx.x >> 6, lane = threadIdx.x & 63;
  const int row = blockIdx.x * 4 + wid;
  float4 v = *(const float4*)(e + (size_t)row * DN + lane * 4);
  float xs[4] = {v.x, v.y, v.z, v.w};
  half4v hv;
  float h2 = 0.f, l2 = 0.f, x2 = 0.f;
#pragma unroll
  for (int j = 0; j < 4; ++j) {
    half_t hh = (half_t)xs[j];
    float lf = xs[j] - (float)hh;
    hv[j] = hh;
    h2 += (float)hh * (float)hh;
    l2 += lf * lf;
    x2 += xs[j] * xs[j];
  }
  const int tile = row >> 7, r = row & 127, kg = lane >> 1, off = (lane & 1) * 4;
  *(half4v*)(eh + (size_t)tile * 32768 + kg * 1024 + r * 8 + off) = hv;
#pragma unroll
  for (int o = 32; o > 0; o >>= 1) {
    h2 += __shfl_down(h2, o);
    l2 += __shfl_down(l2, o);
    x2 += __shfl_down(x2, o);
  }
  if (lane == 0) {
    enorm[row] = x2;
    atomicMax(Wb + 4, __float_as_uint(sqrtf(h2)));
    atomicMax(Wb + 5, __float_as_uint(sqrtf(l2)));
  }
}

// hi-only MFMA distance pass + margin-based candidate collection.
// grid(x = z-tile 256, y = code-tile 64): same-row K-blocks mostly serialized
// across dispatch rounds -> tight running besthh -> few appends.
__global__ __launch_bounds__(256, 4) void k_pass1(
    const half_t* __restrict__ eh, const half_t* __restrict__ zh,
    const float* __restrict__ enorm, const float* __restrict__ znh,
    const float* __restrict__ znl, const float* __restrict__ Wf,
    u64* __restrict__ besthh, u64* __restrict__ cand, u32* __restrict__ cnt) {
  __shared__ __align__(16) half_t L[2][2][4096];  // [buf][A|B][kg4*1024+row*8]
  __shared__ float En[128];
  const int tid = threadIdx.x;
  const int wid = tid >> 6, lane = tid & 63;
  const int l31 = lane & 31, h = lane >> 5;
  const int bn0 = blockIdx.x * 128;  // z rows
  const int bm0 = blockIdx.y * 128;  // codes
  const int wm = (wid & 1) * 64, wn = (wid >> 1) * 64;
  if (tid < 128) En[tid] = enorm[bm0 + tid];

  const half_t* gsrc = (wid < 2 ? eh + (size_t)blockIdx.y * 32768
                                : zh + (size_t)blockIdx.x * 32768) +
                       (wid & 1) * 2048 + lane * 8;
  const int arr = wid >> 1;
  const int dof = (wid & 1) * 2048 + lane * 8;

  float16v acc[2][2] = {};

#define STAGE(c, b)                                                            \
  {                                                                            \
    const half_t* g_ = gsrc + (c) * 4096;                                      \
    half_t* d_ = &L[b][arr][dof];                                              \
    _Pragma("unroll") for (int i_ = 0; i_ < 4; ++i_)                           \
        __builtin_amdgcn_global_load_lds(                                      \
            (const __attribute__((address_space(1))) void*)(g_ + i_ * 512),    \
            (__attribute__((address_space(3))) void*)(d_ + i_ * 512), 16, 0,   \
            0);                                                                \
  }

  STAGE(0, 0)
  for (int c = 0; c < 8; ++c) {
    __syncthreads();
    if (c < 7) STAGE(c + 1, (c + 1) & 1)
    const half_t* A = L[c & 1][0];
    const half_t* B = L[c & 1][1];
#pragma unroll
    for (int ks = 0; ks < 2; ++ks) {
      const int ko = (ks * 2 + h) * 1024;
      half8 af[2], bf[2];
#pragma unroll
      for (int i = 0; i < 2; ++i) {
        af[i] = *(const half8*)(A + ko + (wm + i * 32 + l31) * 8);
        bf[i] = *(const half8*)(B + ko + (wn + i * 32 + l31) * 8);
      }
#pragma unroll
      for (int mi = 0; mi < 2; ++mi)
#pragma unroll
        for (int ni = 0; ni < 2; ++ni)
          acc[mi][ni] = __builtin_amdgcn_mfma_f32_32x32x16_f16(
              af[mi], bf[ni], acc[mi][ni], 0, 0, 0);
    }
  }

  // 32x32 C/D layout: col(z) = lane&31, row(code) = (r&3)+8*(r>>2)+4*h
  u64 key[2];
#pragma unroll
  for (int ni = 0; ni < 2; ++ni) {
    u64 kb = ~0ull;
#pragma unroll
    for (int mi = 0; mi < 2; ++mi)
#pragma unroll
      for (int r = 0; r < 16; ++r) {
        const int row = (r & 3) + 8 * (r >> 2) + 4 * h;
        const int lc = wm + mi * 32 + row;
        const float d = En[lc] - 2.0f * acc[mi][ni][r];
        const u64 kk = ((u64)enc_f(d) << 32) | (u32)(bm0 + lc);
        kb = kk < kb ? kk : kb;
      }
    key[ni] = kb;
  }
#pragma unroll
  for (int ni = 0; ni < 2; ++ni) {
    u64 o = __shfl_xor(key[ni], 32);
    key[ni] = o < key[ni] ? o : key[ni];
  }
  atomicMin(besthh + bn0 + wn + h * 32 + l31, h ? key[1] : key[0]);
  __syncthreads();  // block's atomics complete (barrier drains vmcnt)

  // rescan registers; append codes within provable margin of running best.
  // any besthh snapshot >= final min, so the true argmin is always appended.
  const float maxEh = Wf[4], maxEl = Wf[5];
#pragma unroll
  for (int ni = 0; ni < 2; ++ni) {
    const int cg = bn0 + wn + ni * 32 + l31;
    const float bf = dec_key((u32)(besthh[cg] >> 32));
    const float thr =
        bf + 2.0f * (znh[cg] * maxEl + znl[cg] * (maxEh + maxEl)) + 0.05f;
#pragma unroll
    for (int mi = 0; mi < 2; ++mi)
#pragma unroll
      for (int r = 0; r < 16; ++r) {
        const int row = (r & 3) + 8 * (r >> 2) + 4 * h;
        const int lc = wm + mi * 32 + row;
        const float d = En[lc] - 2.0f * acc[mi][ni][r];
        if (d <= thr) {
          const u32 pos = atomicAdd(cnt, 1u);
          if (pos < CAP)
            cand[pos] =
                ((u64)enc_f(d) << 32) | ((u64)(u32)cg << 13) | (u32)(bm0 + lc);
        }
      }
  }
#undef STAGE
}

// prune candidates vs FINAL besthh+margin; exact fp32 dot for survivors
__global__ __launch_bounds__(256) void k_refine(
    const float* __restrict__ z, const float* __restrict__ emb,
    const float* __restrict__ enorm, const float* __restrict__ znh,
    const float* __restrict__ znl, const float* __restrict__ Wf,
    const u64* __restrict__ besthh, const u64* __restrict__ cand,
    const u32* __restrict__ cnt, u64* __restrict__ best) {
  const int lane = threadIdx.x & 63;
  const u32 gw = blockIdx.x * 4 + (threadIdx.x >> 6);
  const u32 n = min(*cnt, CAP);
  const float maxEh = Wf[4], maxEl = Wf[5];
  for (u32 i = gw; i < n; i += 4096) {
    const u64 cd = cand[i];
    const u32 lo = (u32)cd;
    const int row = (lo >> 13) & 0x7FFF;
    const int code = lo & 0x1FFF;
    const float dhh = dec_key((u32)(cd >> 32));
    const float bf = dec_key((u32)(besthh[row] >> 32));
    const float thr =
        bf + 2.0f * (znh[row] * maxEl + znl[row] * (maxEh + maxEl)) + 0.05f;
    if (dhh > thr) continue;
    float4 zv = *(const float4*)(z + (size_t)row * DN + lane * 4);
    float4 ev = *(const float4*)(emb + (size_t)code * DN + lane * 4);
    float dot = zv.x * ev.x + zv.y * ev.y + zv.z * ev.z + zv.w * ev.w;
    dot = wave_reduce_add(dot);
    if (lane == 0) {
      const float d = enorm[code] - 2.0f * dot;
      atomicMin(best + row, ((u64)enc_f(d) << 32) | (u32)code);
    }
  }
}

// z_q straight-through + loss + indices + cluster histogram
__global__ __launch_bounds__(256) void k_out(const float* __restrict__ z,
                                             const float* __restrict__ emb,
                                             const u64* __restrict__ best,
                                             float* __restrict__ out,
                                             float* __restrict__ Wf,
                                             float* __restrict__ cluster) {
  const int wid = threadIdx.x >> 6, lane = threadIdx.x & 63;
  const int row = blockIdx.x * 4 + wid;
  const int code = (int)((u32)best[row] & 0x1FFF);
  const int d = lane << 2;
  float4 zv = *(const float4*)(z + (size_t)row * DN + d);
  float4 ev = *(const float4*)(emb + (size_t)code * DN + d);
  float4 df = make_float4(ev.x - zv.x, ev.y - zv.y, ev.z - zv.z, ev.w - zv.w);
  float4 st = make_float4(zv.x + df.x, zv.y + df.y, zv.z + df.z, zv.w + df.w);
  *(float4*)(out + (size_t)row * DN + d) = st;
  float sq = df.x * df.x + df.y * df.y + df.z * df.z + df.w * df.w;
  sq = wave_reduce_add(sq);
  if (lane == 0) {
    unsafeAtomicAdd(&Wf[0], sq);
    unsafeAtomicAdd(&cluster[code], 1.0f);
    out[O_IDX + row] = (float)code;
  }
}

// single block: EMA cluster stats + exclusive prefix (for counting sort)
__global__ __launch_bounds__(256) void k_scan(const float* __restrict__ ema_cs,
                                              const float* __restrict__ cluster,
                                              float* __restrict__ newcs,
                                              int* __restrict__ rowstart,
                                              int* __restrict__ cursor,
                                              float* __restrict__ Wf) {
  __shared__ int ssum[256];
  __shared__ float sn[256], sp[256];
  const int t = threadIdx.x;
  const int base = t * 32;
  int s = 0;
  float nsum = 0.f, plsum = 0.f;
  for (int j = 0; j < 32; ++j) {
    float cs = cluster[base + j];
    s += (int)cs;
    float nc = 0.99f * ema_cs[base + j] + 0.01f * cs;
    newcs[base + j] = nc;
    nsum += nc;
    float p = cs * (1.0f / 32768.0f);
    plsum += p * logf(p + 1e-10f);
  }
  ssum[t] = s;
  sn[t] = nsum;
  sp[t] = plsum;
  __syncthreads();
  for (int st = 1; st < 256; st <<= 1) {  // Hillis-Steele inclusive scan
    int v = (t >= st) ? ssum[t - st] : 0;
    __syncthreads();
    ssum[t] += v;
    __syncthreads();
  }
  int off = ssum[t] - s;  // exclusive prefix
  for (int j = 0; j < 32; ++j) {
    rowstart[base + j] = off;
    cursor[base + j] = off;
    off += (int)cluster[base + j];
  }
  for (int st = 128; st > 0; st >>= 1) {
    if (t < st) {
      sn[t] += sn[t + st];
      sp[t] += sp[t + st];
    }
    __syncthreads();
  }
  if (t == 0) {
    Wf[1] = sn[0];
    Wf[2] = sp[0];
  }
}

__global__ __launch_bounds__(256) void k_scatter(const u64* __restrict__ best,
                                                 int* __restrict__ cursor,
                                                 int* __restrict__ rowlist) {
  const int row = blockIdx.x * 256 + threadIdx.x;
  const int code = (int)((u32)best[row] & 0x1FFF);
  const int pos = atomicAdd(cursor + code, 1);
  rowlist[pos] = row;
}

// segmented sum per code -> embsum (stored in out+O_ES region, float2-aligned)
__global__ __launch_bounds__(256) void k_accum(const float* __restrict__ z,
                                               const float* __restrict__ cluster,
                                               const int* __restrict__ rowstart,
                                               const int* __restrict__ rowlist,
                                               float* __restrict__ embsum) {
  const int wid = threadIdx.x >> 6, lane = threadIdx.x & 63;
  const int code = blockIdx.x * 4 + wid;
  const int cnt = (int)cluster[code];
  const int st = rowstart[code];
  float4 a = make_float4(0.f, 0.f, 0.f, 0.f);
  for (int j = 0; j < cnt; ++j) {
    const int row = rowlist[st + j];
    float4 v = *(const float4*)(z + (size_t)row * DN + lane * 4);
    a.x += v.x;
    a.y += v.y;
    a.z += v.z;
    a.w += v.w;
  }
  float* o = embsum + (size_t)code * DN + lane * 4;
  *(float2*)o = make_float2(a.x, a.y);
  *(float2*)(o + 2) = make_float2(a.z, a.w);
}

// embsum aliases out+O_ES (read-before-overwrite per thread) -> no restrict
__global__ __launch_bounds__(256) void k_final(const float* __restrict__ z,
                                               const float* __restrict__ ema_es,
                                               const float* __restrict__ noise,
                                               const int* __restrict__ ridx,
                                               const float* embsum,
                                               const float* __restrict__ newcs,
                                               const float* __restrict__ Wf,
                                               float* out) {
  int gid = blockIdx.x * 256 + threadIdx.x;  // 0 .. KN*64-1
  int k = gid >> 6;
  int d = (gid & 63) << 2;
  float n = Wf[1];
  float nc = newcs[k];
  float cs_sm = (nc + 1e-5f) / (n + (float)KN * 1e-5f) * n;
  bool dead = (nc / n) < (1.0f / (KN * 10.0f));
  size_t o = (size_t)k * DN + d;
  float4 es = *(const float4*)(ema_es + o);
  float2 s01 = *(const float2*)(embsum + o);
  float2 s23 = *(const float2*)(embsum + o + 2);
  float4 nes = make_float4(0.99f * es.x + 0.01f * s01.x,
                           0.99f * es.y + 0.01f * s01.y,
                           0.99f * es.z + 0.01f * s23.x,
                           0.99f * es.w + 0.01f * s23.y);
  float4 ne = make_float4(nes.x / cs_sm, nes.y / cs_sm, nes.z / cs_sm,
                          nes.w / cs_sm);
  if (dead) {  // wave-uniform (one k per wave)
    int r = ridx[k];
    float4 rz = *(const float4*)(z + (size_t)r * DN + d);
    float4 rn = *(const float4*)(noise + o);
    nes = make_float4(rz.x + rn.x, rz.y + rn.y, rz.z + rn.z, rz.w + rn.w);
    ne = nes;
  }
  float* oe = out + O_EMB + o;  // 8B-aligned region -> float2 stores
  *(float2*)(oe) = make_float2(ne.x, ne.y);
  *(float2*)(oe + 2) = make_float2(ne.z, ne.w);
  float* os = out + O_ES + o;
  *(float2*)(os) = make_float2(nes.x, nes.y);
  *(float2*)(os + 2) = make_float2(nes.z, nes.w);
  if ((gid & 63) == 0) out[O_CS + k] = dead ? 1.0f : nc;
  if (gid == 0) {
    out[O_LOSS] = 0.25f * Wf[0] * (1.0f / 8388608.0f);
    out[O_PERP] = expf(-Wf[2]);
  }
}

extern "C" void kernel_launch(void* const* d_in, const int* in_sizes, int n_in,
                              void* d_out, int out_size, void* d_ws,
                              size_t ws_size, hipStream_t stream) {
  const float* z = (const float*)d_in[0];
  const float* emb = (const float*)d_in[1];
  const float* ema_cs = (const float*)d_in[2];
  const float* ema_es = (const float*)d_in[3];
  const float* noise = (const float*)d_in[4];
  const int* ridx = (const int*)d_in[5];
  float* out = (float*)d_out;

  // ws layout (~1.1 MB): Wf[16] cluster[8K] newcs[8K] enorm[8K] znh[32K]
  // znl[32K] rowstart[8K] cursor[8K] rowlist[32K] besthh[32K u64] best[32K u64]
  float* Wf = (float*)d_ws;
  float* cluster = Wf + 16;
  float* newcs = cluster + KN;
  float* enorm = newcs + KN;
  float* znh = enorm + KN;
  float* znl = znh + BN;
  int* rowstart = (int*)(znl + BN);
  int* cursor = rowstart + KN;
  int* rowlist = cursor + KN;
  u64* besthh = (u64*)(rowlist + BN);
  u64* best = besthh + BN;

  // scratch carved from d_out regions overwritten later:
  //  zh pack (16.8MB) in z_q[0..half); cand (16MB) in z_q[half..);
  //  eh pack (4.2MB) in O_EMB+2 (16B-aligned); embsum -> O_ES in place.
  half_t* zh = (half_t*)out;
  u64* cand = (u64*)(out + (size_t)BN * DN / 2);
  half_t* eh = (half_t*)(out + O_EMB + 2);
  float* embsum = out + O_ES;

  hipMemsetAsync(Wf, 0, (16 + KN) * sizeof(float), stream);        // Wf+cluster
  hipMemsetAsync(besthh, 0xFF, 2 * (size_t)BN * sizeof(u64), stream);

  k_prep_z<<<BN / 4, 256, 0, stream>>>(z, zh, znh, znl);
  k_prep_e<<<KN / 4, 256, 0, stream>>>(emb, eh, enorm, (u32*)Wf);
  k_pass1<<<dim3(BN / 128, KN / 128), 256, 0, stream>>>(
      eh, zh, enorm, znh, znl, Wf, besthh, cand, (u32*)Wf + 3);
  k_refine<<<1024, 256, 0, stream>>>(z, emb, enorm, znh, znl, Wf, besthh, cand,
                                     (const u32*)Wf + 3, best);
  k_out<<<BN / 4, 256, 0, stream>>>(z, emb, best, out, Wf, cluster);
  k_scan<<<1, 256, 0, stream>>>(ema_cs, cluster, newcs, rowstart, cursor, Wf);
  k_scatter<<<BN / 256, 256, 0, stream>>>(best, cursor, rowlist);
  k_accum<<<KN / 4, 256, 0, stream>>>(z, cluster, rowstart, rowlist, embsum);
  k_final<<<(KN * 64) / 256, 256, 0, stream>>>(z, ema_es, noise, ridx, embsum,
                                               newcs, Wf, out);
}